// Round 5
// baseline (43.103 us; speedup 1.0000x reference)
//
#include <hip/hip_runtime.h>
#include <cfloat>

// Problem constants: B=32, C=256, L=512, N=1024, S=8
constexpr int Bc = 32;
constexpr int Cc = 256;
constexpr int Lc = 512;
constexpr int Nc = 1024;
constexpr int Sc = 8;

typedef float f4 __attribute__((ext_vector_type(4)));

// ---------------- Kernel 1: transpose (B,C,L) -> (B,L,C) into d_ws ----------
// Block = one 64x64 tile of one batch. Fully coalesced loads and stores.
__global__ __launch_bounds__(256) void transpose_bcl_blc(
    const float* __restrict__ src,   // (B, C, L)
    float*       __restrict__ dst)   // (B, L, C)
{
    __shared__ float tile[64 * 65];  // +1 pad: ds banks ~2-way (free)

    const int blk = blockIdx.x;          // 0..1023
    const int b   = blk >> 5;
    const int r   = blk & 31;
    const int c0  = (r >> 3) << 6;       // 0,64,128,192
    const int l0  = (r & 7) << 6;        // 0..448

    const int tid = threadIdx.x;
    const int tr  = tid >> 4;            // 0..15
    const int tc4 = (tid & 15) << 2;     // 0..60

    #pragma unroll
    for (int pass = 0; pass < 4; ++pass) {
        const int row = tr + (pass << 4);            // c-local 0..63
        f4 v = *(const f4*)(src + ((size_t)(b * Cc + c0 + row)) * Lc + l0 + tc4);
        tile[row * 65 + tc4 + 0] = v.x;              // bank = (row + tc4 + k)%32 -> 2-way
        tile[row * 65 + tc4 + 1] = v.y;
        tile[row * 65 + tc4 + 2] = v.z;
        tile[row * 65 + tc4 + 3] = v.w;
    }
    __syncthreads();
    #pragma unroll
    for (int pass = 0; pass < 4; ++pass) {
        const int pr = tr + (pass << 4);             // l-local 0..63
        f4 w;
        w.x = tile[(tc4 + 0) * 65 + pr];             // bank = (tc4 + k + pr)%32 -> 2-way
        w.y = tile[(tc4 + 1) * 65 + pr];
        w.z = tile[(tc4 + 2) * 65 + pr];
        w.w = tile[(tc4 + 3) * 65 + pr];
        *(f4*)(dst + ((size_t)(b * Lc + l0 + pr)) * Cc + c0 + tc4) = w;
    }
}

// ---------------- Kernel 2: pooling over T(B,L,C) ---------------------------
// Block = (ROI n, half h): 4 waves, wave w computes bin j = 4h+w.
// Lane holds channels [4*lane, 4*lane+4); per position p one wave reads
// T[b][p][0..255] = 1 KB contiguous (16 fully-consumed lines).
__global__ __launch_bounds__(256) void roi_pool_t(
    const float* __restrict__ T,       // (B, L, C)
    const int*   __restrict__ rois,    // (N, 2)
    const int*   __restrict__ roi_idx, // (N,)
    float*       __restrict__ out)     // (N, C, S)
{
    __shared__ float lds[4 * 260];     // [wave][channel], stride 260 keeps f4 writes 16B-aligned

    const int blk = blockIdx.x;        // 0..2047
    const int n   = blk >> 1;
    const int h   = blk & 1;

    const int x1 = rois[2 * n];        // block-uniform scalar loads
    const int x2 = rois[2 * n + 1];
    const int lr = x2 - x1;            // 1..512
    const int b  = roi_idx[n];

    const int tid  = threadIdx.x;
    const int wid  = tid >> 6;
    const int lane = tid & 63;
    const int j    = (h << 2) | wid;   // bin 0..7

    const int s = x1 + ((j * lr) >> 3);                 // bin start
    const int e = x1 + (((j + 1) * lr + Sc - 1) >> 3);  // bin end (> s always)

    const f4* Tp = (const f4*)(T + ((size_t)(b * Lc + s)) * Cc) + lane;

    f4 acc = {-FLT_MAX, -FLT_MAX, -FLT_MAX, -FLT_MAX};
    for (int p = s; p < e; ++p) {
        f4 v = *Tp;
        acc.x = fmaxf(acc.x, v.x);
        acc.y = fmaxf(acc.y, v.y);
        acc.z = fmaxf(acc.z, v.z);
        acc.w = fmaxf(acc.w, v.w);
        Tp += Cc / 4;                  // next position: +1 KB
    }

    // repack: lds[w*260 + c] = bin (4h+w) of channel c
    *(f4*)&lds[wid * 260 + (lane << 2)] = acc;   // aligned, ~2-way banks
    __syncthreads();

    // channel c = tid: gather its 4 bins (4h..4h+3), one aligned f4 store
    const int c = tid;
    f4 rv;
    rv.x = lds[          c];           // bank = c%32, 2 lanes each, distinct addr -> free
    rv.y = lds[260     + c];
    rv.z = lds[520     + c];
    rv.w = lds[780     + c];
    *(f4*)(out + ((size_t)n * Cc + c) * Sc + (h << 2)) = rv;
}

extern "C" void kernel_launch(void* const* d_in, const int* in_sizes, int n_in,
                              void* d_out, int out_size, void* d_ws, size_t ws_size,
                              hipStream_t stream) {
    const float* sentences = (const float*)d_in[0];
    const int*   rois      = (const int*)d_in[1];
    const int*   roi_idx   = (const int*)d_in[2];
    float*       out       = (float*)d_out;
    float*       T         = (float*)d_ws;           // 16 MB scratch (ws >= 256 MiB)

    transpose_bcl_blc<<<Bc * (Cc / 64) * (Lc / 64), 256, 0, stream>>>(sentences, T);
    roi_pool_t<<<Nc * 2, 256, 0, stream>>>(T, rois, roi_idx, out);
}

// Round 6
// 40.738 us; speedup vs baseline: 1.0581x; 1.0581x over previous
//
#include <hip/hip_runtime.h>
#include <cfloat>

// Problem constants: B=32, C=256, L=512, N=1024, S=8
constexpr int Bc = 32;
constexpr int Cc = 256;
constexpr int Lc = 512;
constexpr int Nc = 1024;
constexpr int Sc = 8;

typedef float f4 __attribute__((ext_vector_type(4)));

// ---- Kernel 1: transpose (B,C,L) -> (B,L,C) into d_ws, plus one extra block
//      that counting-sorts ROI indices by batch (deterministic, stable).
__global__ __launch_bounds__(256) void transpose_and_sort(
    const float* __restrict__ src,     // (B, C, L)
    float*       __restrict__ dst,     // (B, L, C)
    const int*   __restrict__ roi_idx, // (N,)
    int*         __restrict__ perm)    // (N,) sorted-slot -> ROI index
{
    __shared__ float tile[64 * 65];    // transpose tile; aliased by sort block

    const int tid = threadIdx.x;

    if (blockIdx.x == Bc * (Cc / 64) * (Lc / 64)) {
        // ---- sort block: stable counting sort of roi_idx by batch ----
        int* bv  = (int*)tile;         // [1024] batch per ROI
        int* cnt = bv + Nc;            // [256] per-(batch, range) counts -> offsets
        #pragma unroll
        for (int q = 0; q < 4; ++q) bv[tid + q * 256] = roi_idx[tid + q * 256];
        __syncthreads();
        // thread t = (v,k): batch v = t>>3, scan range k = t&7 of 128 ROIs
        const int v = tid >> 3, k = tid & 7;
        int c = 0;
        for (int m = 0; m < 128; ++m) c += (bv[k * 128 + m] == v);
        cnt[tid] = c;
        __syncthreads();
        if (tid == 0) {                // exclusive prefix, batch-major order
            int run = 0;
            for (int t = 0; t < 256; ++t) { int x = cnt[t]; cnt[t] = run; run += x; }
        }
        __syncthreads();
        int pos = cnt[tid];
        for (int m = 0; m < 128; ++m) {
            const int i = k * 128 + m;
            if (bv[i] == v) perm[pos++] = i;
        }
        return;
    }

    // ---- transpose blocks (verbatim from R5, proven correct) ----
    const int blk = blockIdx.x;          // 0..1023
    const int b   = blk >> 5;
    const int r   = blk & 31;
    const int c0  = (r >> 3) << 6;       // 0,64,128,192
    const int l0  = (r & 7) << 6;        // 0..448

    const int tr  = tid >> 4;            // 0..15
    const int tc4 = (tid & 15) << 2;     // 0..60

    #pragma unroll
    for (int pass = 0; pass < 4; ++pass) {
        const int row = tr + (pass << 4);            // c-local 0..63
        f4 v = *(const f4*)(src + ((size_t)(b * Cc + c0 + row)) * Lc + l0 + tc4);
        tile[row * 65 + tc4 + 0] = v.x;
        tile[row * 65 + tc4 + 1] = v.y;
        tile[row * 65 + tc4 + 2] = v.z;
        tile[row * 65 + tc4 + 3] = v.w;
    }
    __syncthreads();
    #pragma unroll
    for (int pass = 0; pass < 4; ++pass) {
        const int pr = tr + (pass << 4);             // l-local 0..63
        f4 w;
        w.x = tile[(tc4 + 0) * 65 + pr];
        w.y = tile[(tc4 + 1) * 65 + pr];
        w.z = tile[(tc4 + 2) * 65 + pr];
        w.w = tile[(tc4 + 3) * 65 + pr];
        *(f4*)(dst + ((size_t)(b * Lc + l0 + pr)) * Cc + c0 + tc4) = w;
    }
}

// ---- Kernel 2: pooling over T(B,L,C), batch-grouped + XCD-swizzled --------
// work item w = sortedROI*2 + half; XCD x (= bid%8 round-robin) gets the
// contiguous sorted chunk [x*256, x*256+256) -> ~4 batches = 2 MB, L2-resident.
__global__ __launch_bounds__(256) void roi_pool_t(
    const float* __restrict__ T,       // (B, L, C)
    const int*   __restrict__ rois,    // (N, 2)
    const int*   __restrict__ perm,    // (N,)
    const int*   __restrict__ roi_idx, // (N,)
    float*       __restrict__ out)     // (N, C, S)
{
    __shared__ float lds[4 * 260];

    const int bid  = blockIdx.x;               // 0..2047
    const int work = ((bid & 7) << 8) | (bid >> 3);
    const int n    = perm[work >> 1];
    const int h    = work & 1;

    const int x1 = rois[2 * n];        // block-uniform scalar loads
    const int x2 = rois[2 * n + 1];
    const int lr = x2 - x1;            // 1..512
    const int b  = roi_idx[n];

    const int tid  = threadIdx.x;
    const int wid  = tid >> 6;
    const int lane = tid & 63;
    const int j    = (h << 2) | wid;   // bin 0..7

    const int s = x1 + ((j * lr) >> 3);                 // bin start
    const int e = x1 + (((j + 1) * lr + Sc - 1) >> 3);  // bin end (> s)

    const f4* Tp = (const f4*)(T + ((size_t)(b * Lc + s)) * Cc) + lane;

    f4 acc = {-FLT_MAX, -FLT_MAX, -FLT_MAX, -FLT_MAX};
    for (int p = s; p < e; ++p) {
        f4 v = *Tp;
        acc.x = fmaxf(acc.x, v.x);
        acc.y = fmaxf(acc.y, v.y);
        acc.z = fmaxf(acc.z, v.z);
        acc.w = fmaxf(acc.w, v.w);
        Tp += Cc / 4;                  // next position: +1 KB
    }

    *(f4*)&lds[wid * 260 + (lane << 2)] = acc;
    __syncthreads();

    const int c = tid;
    f4 rv;
    rv.x = lds[      c];
    rv.y = lds[260 + c];
    rv.z = lds[520 + c];
    rv.w = lds[780 + c];
    *(f4*)(out + ((size_t)n * Cc + c) * Sc + (h << 2)) = rv;
}

extern "C" void kernel_launch(void* const* d_in, const int* in_sizes, int n_in,
                              void* d_out, int out_size, void* d_ws, size_t ws_size,
                              hipStream_t stream) {
    const float* sentences = (const float*)d_in[0];
    const int*   rois      = (const int*)d_in[1];
    const int*   roi_idx   = (const int*)d_in[2];
    float*       out       = (float*)d_out;

    float* T    = (float*)d_ws;                              // 16 MB
    int*   perm = (int*)((char*)d_ws + (size_t)Bc * Cc * Lc * 4);  // after T

    transpose_and_sort<<<Bc * (Cc / 64) * (Lc / 64) + 1, 256, 0, stream>>>(
        sentences, T, roi_idx, perm);
    roi_pool_t<<<Nc * 2, 256, 0, stream>>>(T, rois, perm, roi_idx, out);
}

// Round 7
// 26.692 us; speedup vs baseline: 1.6148x; 1.5262x over previous
//
#include <hip/hip_runtime.h>
#include <cfloat>

// Problem constants: B=32, C=256, L=512, N=1024, S=8
constexpr int Bc = 32;
constexpr int Cc = 256;
constexpr int Lc = 512;
constexpr int Nc = 1024;
constexpr int Sc = 8;

constexpr int CT     = 16;    // channels per block
constexpr int STRIDE = 516;   // LDS row stride (floats): 2064 B = 16B-aligned;
                              // bank = (4*c + p) % 32 -> 8 distinct banks per j-group

typedef float f4 __attribute__((ext_vector_type(4)));

// Block = (batch b, 16-channel tile). Phase 0: compact ROI list for b.
// Phase 1: stage rows [b, c0..c0+16) x [0,512) into LDS (each input byte
// read exactly once, fully coalesced). Phase 2: per-ROI bin-max over LDS,
// thread = (roi_slot, channel, bin), two independent fmax chains.
__global__ __launch_bounds__(256) void roi_pool_fused(
    const float* __restrict__ sentences,   // (B, C, L)
    const int*   __restrict__ rois,        // (N, 2)
    const int*   __restrict__ roi_idx,     // (N,)
    float*       __restrict__ out)         // (N, C, S)
{
    __shared__ float rowbuf[CT * STRIDE];  // 33,024 B
    __shared__ int   list[Nc];             // 4 KB (handles worst-case all-one-batch)
    __shared__ int   cnt;

    const int bid = blockIdx.x;            // 0..511
    const int b   = bid >> 4;              // batch
    const int c0  = (bid & 15) * CT;       // channel tile base
    const int tid = threadIdx.x;

    if (tid == 0) cnt = 0;
    __syncthreads();

    // ---- Phase 0: compaction (order-free; values don't depend on order) ----
    {
        const int4* ri = (const int4*)roi_idx;
        int4 v = ri[tid];                  // 256 threads x 4 = N
        if (v.x == b) list[atomicAdd(&cnt, 1)] = 4 * tid + 0;
        if (v.y == b) list[atomicAdd(&cnt, 1)] = 4 * tid + 1;
        if (v.z == b) list[atomicAdd(&cnt, 1)] = 4 * tid + 2;
        if (v.w == b) list[atomicAdd(&cnt, 1)] = 4 * tid + 3;
    }

    // ---- Phase 1: stage 16 rows x 512 floats, coalesced f4 ----
    {
        const f4* src = (const f4*)(sentences + ((size_t)b * Cc + c0) * Lc);
        #pragma unroll
        for (int i = 0; i < (CT * Lc / 4) / 256; ++i) {   // 8 chunks/thread
            const int idx = tid + i * 256;                // 0..2047
            const int r   = idx >> 7;                     // row 0..15
            const int q   = idx & 127;                    // f4 slot in row
            f4 v = src[r * (Lc / 4) + q];                 // wave: 1KB contiguous
            *(f4*)(rowbuf + r * STRIDE + 4 * q) = v;      // 16B-aligned ds_write_b128
        }
    }
    __syncthreads();

    // ---- Phase 2: bin maxes ----
    const int rp = tid >> 7;               // ROI slot 0/1 (wave-uniform)
    const int cl = (tid >> 3) & 15;        // channel within tile
    const int j  = tid & 7;                // bin
    const float* row = rowbuf + cl * STRIDE;

    const int m = cnt;                     // visible after the barrier above
    for (int i = rp; i < m; i += 2) {
        const int n  = list[i];
        const int x1 = rois[2 * n];
        const int x2 = rois[2 * n + 1];
        const int lr = x2 - x1;            // 1..512
        const int s  = x1 + ((j * lr) >> 3);
        const int e  = x1 + (((j + 1) * lr + Sc - 1) >> 3);   // > s always

        float m0 = -FLT_MAX, m1 = -FLT_MAX;
        int p = s;
        for (; p + 2 <= e; p += 2) {       // two independent chains
            m0 = fmaxf(m0, row[p]);
            m1 = fmaxf(m1, row[p + 1]);
        }
        if (p < e) m0 = fmaxf(m0, row[p]);

        // lanes (cl,j) -> 64 consecutive floats: coalesced 256B store
        out[(size_t)n * (Cc * Sc) + (c0 + cl) * Sc + j] = fmaxf(m0, m1);
    }
}

extern "C" void kernel_launch(void* const* d_in, const int* in_sizes, int n_in,
                              void* d_out, int out_size, void* d_ws, size_t ws_size,
                              hipStream_t stream) {
    const float* sentences = (const float*)d_in[0];
    const int*   rois      = (const int*)d_in[1];
    const int*   roi_idx   = (const int*)d_in[2];
    float*       out       = (float*)d_out;

    roi_pool_fused<<<Bc * (Cc / CT), 256, 0, stream>>>(sentences, rois, roi_idx, out);
}

// Round 8
// 19.709 us; speedup vs baseline: 2.1869x; 1.3543x over previous
//
#include <hip/hip_runtime.h>
#include <cfloat>

// Problem constants: B=32, C=256, L=512, N=1024, S=8
constexpr int Bc = 32;
constexpr int Cc = 256;
constexpr int Lc = 512;
constexpr int Nc = 1024;
constexpr int Sc = 8;

constexpr int CT     = 16;    // channels per block
constexpr int STRIDE = 516;   // LDS row stride (floats); even -> 8B-aligned f2 at even p

typedef float f4 __attribute__((ext_vector_type(4)));
typedef float f2 __attribute__((ext_vector_type(2)));

// Block = (batch b, 16-channel tile, half). 1024 blocks = 4/CU.
// Ballot-based deterministic compaction (no LDS atomics), coalesced staging,
// f2 LDS bin-walk. Each block processes bucket items with (i & 1) == half.
__global__ __launch_bounds__(256) void roi_pool_fused2(
    const float* __restrict__ sentences,   // (B, C, L)
    const int*   __restrict__ rois,        // (N, 2)
    const int*   __restrict__ roi_idx,     // (N,)
    float*       __restrict__ out)         // (N, C, S)
{
    __shared__ float rowbuf[CT * STRIDE];  // 33,024 B
    __shared__ int   list[Nc];             // 4 KB
    __shared__ int   wcnt[16];             // per (round, wave) match counts

    const int bid  = blockIdx.x;           // 0..1023
    const int b    = bid >> 5;             // batch
    const int ct   = (bid >> 1) & 15;      // channel tile
    const int half = bid & 1;
    const int c0   = ct * CT;

    const int tid  = threadIdx.x;
    const int lane = tid & 63;
    const int w    = tid >> 6;             // wave 0..3

    // ---- compaction scan: 4 rounds x 256 threads covers N=1024 ----
    int myidx[4], mypos[4];
    #pragma unroll
    for (int q = 0; q < 4; ++q) {
        const int i = q * 256 + tid;
        const int v = roi_idx[i];                         // coalesced, L2-hot
        const unsigned long long mask = __ballot(v == b);
        mypos[q] = __popcll(mask & ((1ull << lane) - 1ull));
        myidx[q] = (v == b) ? i : -1;
        if (lane == 0) wcnt[q * 4 + w] = __popcll(mask);
    }

    // ---- staging: 16 rows x 512 floats, coalesced f4 (overlaps with above) ----
    {
        const f4* src = (const f4*)(sentences + ((size_t)b * Cc + c0) * Lc);
        #pragma unroll
        for (int i = 0; i < (CT * Lc / 4) / 256; ++i) {   // 8 chunks/thread
            const int idx = tid + i * 256;
            const int r   = idx >> 7;                     // row 0..15
            const int q   = idx & 127;                    // f4 slot
            f4 v = src[r * (Lc / 4) + q];
            *(f4*)(rowbuf + r * STRIDE + 4 * q) = v;
        }
    }
    __syncthreads();   // wcnt + rowbuf visible

    // ---- deterministic prefix over wcnt (redundant per thread, registers) ----
    int wb0 = 0, wb1 = 0, wb2 = 0, wb3 = 0, run = 0;
    #pragma unroll
    for (int t = 0; t < 16; ++t) {
        if (t == w)      wb0 = run;
        if (t == 4 + w)  wb1 = run;
        if (t == 8 + w)  wb2 = run;
        if (t == 12 + w) wb3 = run;
        run += wcnt[t];                    // LDS broadcast read (uniform)
    }
    const int m = run;                     // bucket size for batch b

    if (myidx[0] >= 0) list[wb0 + mypos[0]] = myidx[0];
    if (myidx[1] >= 0) list[wb1 + mypos[1]] = myidx[1];
    if (myidx[2] >= 0) list[wb2 + mypos[2]] = myidx[2];
    if (myidx[3] >= 0) list[wb3 + mypos[3]] = myidx[3];
    __syncthreads();   // list visible

    // ---- bin maxes: thread = (roi-slot rp, channel cl, bin j) ----
    const int rp = tid >> 7;               // 0/1 (wave-uniform)
    const int cl = (tid >> 3) & 15;
    const int j  = tid & 7;
    const float* row = rowbuf + cl * STRIDE;

    for (int i = half + 2 * rp; i < m; i += 4) {
        const int n  = list[i];
        const int x1 = rois[2 * n];        // wave-uniform
        const int x2 = rois[2 * n + 1];
        const int lr = x2 - x1;            // 1..512
        const int s  = x1 + ((j * lr) >> 3);
        const int e  = x1 + (((j + 1) * lr + Sc - 1) >> 3);   // > s always

        float m0 = -FLT_MAX, m1 = -FLT_MAX;
        int p = s;
        if (p & 1) { m0 = row[p]; ++p; }                  // align to 8B
        for (; p + 4 <= e; p += 4) {                      // two f2 loads in flight
            f2 a = *(const f2*)(row + p);
            f2 c = *(const f2*)(row + p + 2);
            m0 = fmaxf(m0, fmaxf(a.x, a.y));
            m1 = fmaxf(m1, fmaxf(c.x, c.y));
        }
        if (p + 2 <= e) {
            f2 a = *(const f2*)(row + p);
            m0 = fmaxf(m0, fmaxf(a.x, a.y));
            p += 2;
        }
        if (p < e) m0 = fmaxf(m0, row[p]);

        // wave lanes (cl,j) -> 64 consecutive floats: coalesced 256B store
        out[(size_t)n * (Cc * Sc) + (c0 + cl) * Sc + j] = fmaxf(m0, m1);
    }
}

extern "C" void kernel_launch(void* const* d_in, const int* in_sizes, int n_in,
                              void* d_out, int out_size, void* d_ws, size_t ws_size,
                              hipStream_t stream) {
    const float* sentences = (const float*)d_in[0];
    const int*   rois      = (const int*)d_in[1];
    const int*   roi_idx   = (const int*)d_in[2];
    float*       out       = (float*)d_out;

    roi_pool_fused2<<<Bc * (Cc / CT) * 2, 256, 0, stream>>>(sentences, rois, roi_idx, out);
}